// Round 2
// baseline (59.598 us; speedup 1.0000x reference)
//
#include <hip/hip_runtime.h>

// BaseGraph (NRI-style node2edge/edge2node) on the complete graph minus
// diagonal, normalize-by-N. Closed form (receivers/senders encode the fixed
// complete graph, so they are unused):
//   out[b,n,0:D]   = (N-1)/N * x[b,n,:]
//   out[b,n,D:2D]  = (sum_j x[b,j,:] - x[b,n,:]) / N
//
// R2 -> R3: FUSED single dispatch. The old 2-kernel split serialized on a
// dependency edge (partial-sum kernel -> streaming kernel) whose launch/drain
// bubble dominated: ideal HBM traffic is only ~3 MiB (~0.5 us at 6.3 TB/s),
// yet measured 58.8 us. Since one batch of x is only 128 KB (L2-resident),
// every block now redundantly computes the full batch sum itself (32-deep
// unrolled float4 loop + one 4 KB LDS fold + one __syncthreads), then streams
// its 16-row slice of the output. Redundant read volume: 128 blocks x 128 KB
// = 16 MB of L2/L3 traffic (~0.5 us aggregate at 34.5 TB/s) -- cheap vs. a
// second dispatch. Workspace P eliminated.
//
// R3 -> R4: unchanged resubmission. Rounds 2 and 3 both hit
// GPUAcquisitionTimeout, so this design has never been measured; submitting
// it unmodified to get a clean first measurement before touching anything.

constexpr int BATCH = 8;
constexpr int NNODE = 256;
constexpr int DFEAT = 128;
constexpr int V4 = DFEAT / 4;          // 32 float4 per row
constexpr int SPLIT = 16;              // blocks per batch
constexpr int RPB = NNODE / SPLIT;     // 16 output rows per block
constexpr int GROUPS = 8;              // 256 threads / 32 lanes-per-row

__global__ void __launch_bounds__(256) fused_basegraph_kernel(
    const float4* __restrict__ x4, float4* __restrict__ out4) {
  const int b = blockIdx.x >> 4;                 // SPLIT == 16
  const int c = blockIdx.x & (SPLIT - 1);
  const int dv = threadIdx.x & (V4 - 1);         // float4 column 0..31
  const int g = threadIdx.x >> 5;                // row group 0..7

  const float4* xb = x4 + (size_t)b * NNODE * V4;

  // ---- Phase A: full batch sum S[b][dv] (every block computes it) ----
  // Group g sums rows {g, g+8, g+16, ...}: each 32-lane group issues one
  // contiguous 512 B load per iteration; 32 independent loads pipeline.
  float4 acc = make_float4(0.f, 0.f, 0.f, 0.f);
#pragma unroll
  for (int k = 0; k < NNODE / GROUPS; ++k) {     // 32 iterations
    const float4 v = xb[(size_t)(g + GROUPS * k) * V4 + dv];
    acc.x += v.x;
    acc.y += v.y;
    acc.z += v.z;
    acc.w += v.w;
  }

  __shared__ float4 lds[GROUPS][V4];             // 4 KB
  lds[g][dv] = acc;
  __syncthreads();

  float4 S = lds[0][dv];
#pragma unroll
  for (int p = 1; p < GROUPS; ++p) {
    const float4 t = lds[p][dv];
    S.x += t.x;
    S.y += t.y;
    S.z += t.z;
    S.w += t.w;
  }

  // ---- Phase B: stream this block's 16 rows ----
  constexpr float kRecvScale = (float)(NNODE - 1) / (float)NNODE;  // 255/256
  constexpr float kInvN = 1.0f / (float)NNODE;

  const int r0 = c * RPB;
  float4* ob = out4 + (size_t)b * NNODE * (2 * V4);
#pragma unroll
  for (int k = 0; k < RPB / GROUPS; ++k) {       // 2 iterations
    const int r = r0 + g + GROUPS * k;
    const float4 v = xb[(size_t)r * V4 + dv];    // L1/L2-hot (read in phase A)
    float4 h1, h2;
    h1.x = v.x * kRecvScale;
    h1.y = v.y * kRecvScale;
    h1.z = v.z * kRecvScale;
    h1.w = v.w * kRecvScale;
    h2.x = (S.x - v.x) * kInvN;
    h2.y = (S.y - v.y) * kInvN;
    h2.z = (S.z - v.z) * kInvN;
    h2.w = (S.w - v.w) * kInvN;
    float4* orow = ob + (size_t)r * (2 * V4);
    orow[dv] = h1;                 // first half: receiver self-features
    orow[V4 + dv] = h2;            // second half: normalized sender sum
  }
}

extern "C" void kernel_launch(void* const* d_in, const int* in_sizes, int n_in,
                              void* d_out, int out_size, void* d_ws,
                              size_t ws_size, hipStream_t stream) {
  const float4* x4 = (const float4*)d_in[0];
  // d_in[1] (receivers) / d_in[2] (senders): fixed complete graph; unused.
  float4* out4 = (float4*)d_out;
  (void)d_ws;
  (void)ws_size;

  fused_basegraph_kernel<<<BATCH * SPLIT, 256, 0, stream>>>(x4, out4);
}

// Round 3
// 59.322 us; speedup vs baseline: 1.0047x; 1.0047x over previous
//
#include <hip/hip_runtime.h>

// BaseGraph (NRI-style node2edge/edge2node) on the complete graph minus
// diagonal, normalize-by-N. Closed form (receivers/senders encode the fixed
// complete graph, so they are unused):
//   out[b,n,0:D]   = (N-1)/N * x[b,n,:]
//   out[b,n,D:2D]  = (sum_j x[b,j,:] - x[b,n,:]) / N
//
// R4 measurement: fused 1-dispatch kernel = 59.6 us vs old 2-dispatch 58.8 us
// -> NEUTRAL. rocprof top-5 are all __amd_rocclr_fillBufferAligned, 40 us
// each, 256 MiB writes at 82-84% HBM peak: the harness's per-iteration
// workspace poison fill dominates the timed region and is itself
// roofline-bound. Our kernel is <40 us (absent from top-5; modeled ~5 us).
//
// R4 -> R5: falsification test of the external-floor theory with a strictly
// cheaper kernel:
//   - SPLIT 16 -> 32: 256 blocks x 256 thr (better CU spread, Phase-B tail
//     halves to exactly 1 row per 32-lane group).
//   - Phase B consumes its row from a register captured during Phase A
//     (row 8c+g is Phase-A iteration k==c for group g; uniform scalar branch
//     per unrolled iter, ~free) -- zero x reloads in Phase B.
// Prediction: dur unchanged (57-61 us) because the floor is external; if so,
// next round declares roofline.

constexpr int BATCH = 8;
constexpr int NNODE = 256;
constexpr int DFEAT = 128;
constexpr int V4 = DFEAT / 4;          // 32 float4 per row
constexpr int SPLIT = 32;              // blocks per batch
constexpr int RPB = NNODE / SPLIT;     // 8 output rows per block
constexpr int GROUPS = 8;              // 256 threads / 32 lanes-per-row

__global__ void __launch_bounds__(256) fused_basegraph_kernel(
    const float4* __restrict__ x4, float4* __restrict__ out4) {
  const int b = blockIdx.x >> 5;                 // SPLIT == 32
  const int c = blockIdx.x & (SPLIT - 1);
  const int dv = threadIdx.x & (V4 - 1);         // float4 column 0..31
  const int g = threadIdx.x >> 5;                // row group 0..7

  const float4* xb = x4 + (size_t)b * NNODE * V4;

  // ---- Phase A: full batch sum S[b][dv] (every block computes it) ----
  // Group g sums rows {g, g+8, g+16, ...}: each 32-lane group issues one
  // contiguous 512 B load per iteration; 32 independent loads pipeline.
  // x[b] is 128 KB -> L2-resident; 256 blocks x 128 KB = 32 MB of L2 traffic
  // (~1 us aggregate at 34.5 TB/s).
  float4 acc = make_float4(0.f, 0.f, 0.f, 0.f);
  float4 mine = make_float4(0.f, 0.f, 0.f, 0.f);
#pragma unroll
  for (int k = 0; k < NNODE / GROUPS; ++k) {     // 32 iterations
    const float4 v = xb[(size_t)(g + GROUPS * k) * V4 + dv];
    if (k == c) mine = v;   // row 8c+g == Phase-B row for this thread
    acc.x += v.x;
    acc.y += v.y;
    acc.z += v.z;
    acc.w += v.w;
  }

  __shared__ float4 lds[GROUPS][V4];             // 4 KB
  lds[g][dv] = acc;
  __syncthreads();

  float4 S = lds[0][dv];
#pragma unroll
  for (int p = 1; p < GROUPS; ++p) {
    const float4 t = lds[p][dv];
    S.x += t.x;
    S.y += t.y;
    S.z += t.z;
    S.w += t.w;
  }

  // ---- Phase B: write this thread's single row slice ----
  constexpr float kRecvScale = (float)(NNODE - 1) / (float)NNODE;  // 255/256
  constexpr float kInvN = 1.0f / (float)NNODE;

  const int r = c * RPB + g;                     // == 8c + g
  float4 h1, h2;
  h1.x = mine.x * kRecvScale;
  h1.y = mine.y * kRecvScale;
  h1.z = mine.z * kRecvScale;
  h1.w = mine.w * kRecvScale;
  h2.x = (S.x - mine.x) * kInvN;
  h2.y = (S.y - mine.y) * kInvN;
  h2.z = (S.z - mine.z) * kInvN;
  h2.w = (S.w - mine.w) * kInvN;

  float4* orow = out4 + ((size_t)b * NNODE + r) * (2 * V4);
  orow[dv] = h1;                 // first half: receiver self-features
  orow[V4 + dv] = h2;            // second half: normalized sender sum
}

extern "C" void kernel_launch(void* const* d_in, const int* in_sizes, int n_in,
                              void* d_out, int out_size, void* d_ws,
                              size_t ws_size, hipStream_t stream) {
  const float4* x4 = (const float4*)d_in[0];
  // d_in[1] (receivers) / d_in[2] (senders): fixed complete graph; unused.
  float4* out4 = (float4*)d_out;
  (void)d_ws;
  (void)ws_size;

  fused_basegraph_kernel<<<BATCH * SPLIT, 256, 0, stream>>>(x4, out4);
}